// Round 12
// baseline (292.156 us; speedup 1.0000x reference)
//
#include <hip/hip_runtime.h>
#include <hip/hip_bf16.h>
#include <hip/hip_fp16.h>
#include <math.h>

#ifndef M_PI
#define M_PI 3.14159265358979323846
#endif

// Problem constants
#define NN 10000      // nodes
#define NE 160000     // edges
#define NC 16         // channels
#define NQ 5          // 2*order+1
#define NFR 10        // N_FREQ * N_RINGS
#define CQ 80         // NC*NQ
#define OP 80         // outputs per node
#define KTOT 800      // GEMM K
#define WSZ 64000     // 80*800 weight elements

#define MT 32         // edges per block (one wave, 2 m-tiles)
#define CSTRIDE 168   // chunk row stride in fp16 elems (160 + 8 pad)

typedef __attribute__((ext_vector_type(8))) _Float16 f16x8;
typedef __attribute__((ext_vector_type(4))) float f32x4;

// RNE float->fp16 (values well within fp16 range)
static __device__ __forceinline__ unsigned short f2h_u(float f) {
    return __builtin_bit_cast(unsigned short, (_Float16)f);
}
static __device__ __forceinline__ unsigned pack2h(float lo, float hi) {
    return (unsigned)f2h_u(lo) | ((unsigned)f2h_u(hi) << 16);
}

// ---------------------------------------------------------------------------
// Merged init kernel: zero agg1+agg2 (1.6M floats, contiguous) AND build the
// fragment-ordered fp16 W tables (identical mapping to R10/R11 — verified):
//   Wt_frag[((ks*5+nt)*64 + lane)*8 + j] = fp16(W at n=16*nt+lrow,
//                                               k = 32*ks + 8*quad + j)
// ---------------------------------------------------------------------------
__global__ void init_ws(const float* __restrict__ W1, const float* __restrict__ W2,
                        unsigned short* __restrict__ Wt1, unsigned short* __restrict__ Wt2,
                        float4* __restrict__ aggz) {
    int i = blockIdx.x * blockDim.x + threadIdx.x;
    if (i < 400000) aggz[i] = make_float4(0.f, 0.f, 0.f, 0.f);  // 6.4 MB zero
    if (i >= WSZ) return;
    int j    = i & 7;
    int lane = (i >> 3) & 63;
    int grp  = i >> 9;           // ks*5 + nt
    int ks   = grp / 5;
    int nt   = grp % 5;
    int quad = lane >> 4;
    int lrow = lane & 15;
    int n    = 16 * nt + lrow;
    int k    = 32 * ks + 8 * quad + j;   // natural k
    int fr = k / CQ, cq = k % CQ;
    int c = cq / NQ, q = cq % NQ;
    int f = fr / 2,  r = fr % 2;
    int o = n / NQ,  p = n % NQ;
    int src = ((((o * NC + c) * NQ + p) * NQ + q) * 5 + f) * 2 + r;
    Wt1[i] = f2h_u(W1[src]);
    Wt2[i] = f2h_u(W2[src]);
}

// ---------------------------------------------------------------------------
// Edge conv v11: single-wave blocks, 32 edges/wave = TWO m-tiles per wave,
// each B-fragment loaded once and fed to both MFMAs (halves L2 B-traffic,
// R11's binding constraint: 250->125 KB per 32 edges). K staged in 5 chunks
// of 160 (=2 fr) as in R11 (bit-identical values & ks order). Single-wave
// __syncthreads = cheap waitcnt, no cross-wave barrier drain.
// Staging: 2 threads/edge, each owns cq half [40*half, 40*half+40).
// ---------------------------------------------------------------------------
__global__ __launch_bounds__(64)
void edge_conv_mfma(const float* __restrict__ xin, const int* __restrict__ ei,
                    const float* __restrict__ pre, const float* __restrict__ phi_arr,
                    const unsigned short* __restrict__ Wt, float* __restrict__ y) {
    __shared__ __align__(16) unsigned short A_s[MT * CSTRIDE];  // 10,752 B
    __shared__ int dst_s[MT];

    const int tid = threadIdx.x;
    const int e0 = blockIdx.x * MT;     // NE = 5000 * 32 exactly

    // ---- per-edge prep: 2 threads/edge, half of cq each ----
    const int el   = tid >> 1;          // local edge 0..31
    const int half = tid & 1;           // cq half [40*half, 40*half+40)
    const int e    = e0 + el;
    const int src  = ei[2 * e];
    if (half == 0) dst_s[el] = ei[2 * e + 1];

    float s1, c1;
    sincosf(phi_arr[e], &s1, &c1);
    const float c2 = c1 * c1 - s1 * s1;
    const float s2 = 2.0f * c1 * s1;

    float xt[40];                        // 8 channels of transported features
    {
        const float4* xp = (const float4*)(xin + (size_t)src * CQ + 40 * half);
        #pragma unroll
        for (int k4 = 0; k4 < 10; ++k4) {
            float4 v = xp[k4];
            xt[4 * k4 + 0] = v.x; xt[4 * k4 + 1] = v.y;
            xt[4 * k4 + 2] = v.z; xt[4 * k4 + 3] = v.w;
        }
        #pragma unroll
        for (int cc = 0; cc < 8; ++cc) {
            float a1 = xt[cc * 5 + 1], b1 = xt[cc * 5 + 2];
            float a2 = xt[cc * 5 + 3], b2 = xt[cc * 5 + 4];
            xt[cc * 5 + 1] = c1 * a1 - s1 * b1;
            xt[cc * 5 + 2] = s1 * a1 + c1 * b1;
            xt[cc * 5 + 3] = c2 * a2 - s2 * b2;
            xt[cc * 5 + 4] = s2 * a2 + c2 * b2;
        }
    }
    float tv[NFR];
    #pragma unroll
    for (int fr = 0; fr < NFR; ++fr) tv[fr] = pre[(size_t)e * NFR + fr];

    // ---- GEMM lane mapping: this wave covers m0=0 (edges 0-15) and
    //      m0=16 (edges 16-31), sharing every B fragment ----
    const int lane = tid;
    const int lrow = lane & 15;
    const int quad = lane >> 4;

    f32x4 acc0[5], acc1[5];
    #pragma unroll
    for (int nt = 0; nt < 5; ++nt) {
        acc0[nt] = (f32x4){0.f, 0.f, 0.f, 0.f};
        acc1[nt] = (f32x4){0.f, 0.f, 0.f, 0.f};
    }

    const f16x8* __restrict__ wf = (const f16x8*)Wt;
    const unsigned short* As_row0 = &A_s[lrow * CSTRIDE];
    const unsigned short* As_row1 = &A_s[(16 + lrow) * CSTRIDE];

    #pragma unroll
    for (int ch = 0; ch < 5; ++ch) {
        // stage chunk ch: fr = 2ch+frl, k-window [160*ch, 160*ch+160)
        #pragma unroll
        for (int frl = 0; frl < 2; ++frl) {
            const float tf = tv[2 * ch + frl];
            uint2* dp = (uint2*)&A_s[el * CSTRIDE + frl * CQ + 40 * half];
            #pragma unroll
            for (int j = 0; j < 10; ++j) {
                unsigned lo = pack2h(xt[4 * j + 0] * tf, xt[4 * j + 1] * tf);
                unsigned hi = pack2h(xt[4 * j + 2] * tf, xt[4 * j + 3] * tf);
                dp[j] = make_uint2(lo, hi);
            }
        }
        __syncthreads();   // single-wave: compiles to cheap waitcnt

        #pragma unroll
        for (int s = 0; s < 5; ++s) {
            f16x8 a0 = *(const f16x8*)(As_row0 + 32 * s + 8 * quad);
            f16x8 a1 = *(const f16x8*)(As_row1 + 32 * s + 8 * quad);
            #pragma unroll
            for (int nt = 0; nt < 5; ++nt) {
                f16x8 b = wf[((5 * ch + s) * 5 + nt) * 64 + lane];
                acc0[nt] = __builtin_amdgcn_mfma_f32_16x16x32_f16(a0, b, acc0[nt], 0, 0, 0);
                acc1[nt] = __builtin_amdgcn_mfma_f32_16x16x32_f16(a1, b, acc1[nt], 0, 0, 0);
            }
        }
        __syncthreads();   // protect A_s before next chunk overwrite
    }

    // ---- scatter: C/D col=lrow -> op, row=quad*4+r -> edge row ----
    #pragma unroll
    for (int r = 0; r < 4; ++r) {
        const int er = 4 * quad + r;
        float* yd0 = y + (size_t)dst_s[er] * OP + lrow;
        float* yd1 = y + (size_t)dst_s[16 + er] * OP + lrow;
        #pragma unroll
        for (int nt = 0; nt < 5; ++nt) {
            atomicAdd(yd0 + 16 * nt, acc0[nt][r]);
            atomicAdd(yd1 + 16 * nt, acc1[nt][r]);
        }
    }
}

// ---------------------------------------------------------------------------
// Fused epilogue: per (n,c) thread computes
//   v[p] = agg[n,c,p] + selfint(x[n])·Ws[c] + (p==0)b[c] (+ res[n,c,p])
// then the 7-sample regular nonlinearity, writing out[n,c,:].
// Replaces the separate selfint dispatch + one full y pass.
// ---------------------------------------------------------------------------
__global__ void nonlin_fused(const float* __restrict__ agg, const float* __restrict__ xin,
                             const float* __restrict__ Ws, const float* __restrict__ b,
                             const float* __restrict__ res, float* __restrict__ out) {
    __shared__ float ws_s[NC * NC * NQ * NQ];  // 25.6 KB
    const int tid = threadIdx.x;
    for (int i = tid; i < NC * NC * NQ * NQ; i += blockDim.x) ws_s[i] = Ws[i];
    __syncthreads();

    int idx = blockIdx.x * blockDim.x + tid;   // over N*C = 160000
    if (idx >= NN * NC) return;
    int n = idx / NC, c = idx % NC;

    float a0, a1v, a2v, a3, a4;
    {
        const float* ap = agg + (size_t)n * OP + c * NQ;
        a0 = ap[0]; a1v = ap[1]; a2v = ap[2]; a3 = ap[3]; a4 = ap[4];
        a0 += b[c];
        // self-interaction: out ch o=c; ws_s[c*400 + c'*25 + p*5 + q]
        const float* xrow = xin + (size_t)n * CQ;
        const float* wsc = ws_s + c * 400;
        #pragma unroll
        for (int cp = 0; cp < NC; ++cp) {
            #pragma unroll
            for (int q = 0; q < NQ; ++q) {
                float xv = xrow[cp * NQ + q];
                const float* w = wsc + cp * 25 + q;
                a0  = fmaf(xv, w[0],  a0);
                a1v = fmaf(xv, w[5],  a1v);
                a2v = fmaf(xv, w[10], a2v);
                a3  = fmaf(xv, w[15], a3);
                a4  = fmaf(xv, w[20], a4);
            }
        }
        if (res != nullptr) {
            const float* rp = res + (size_t)n * CQ + c * NQ;
            a0 += rp[0]; a1v += rp[1]; a2v += rp[2]; a3 += rp[3]; a4 += rp[4];
        }
    }

    float o0 = 0.f, o1 = 0.f, o2 = 0.f, o3 = 0.f, o4 = 0.f;
    #pragma unroll
    for (int k = 0; k < 7; ++k) {
        float th = (float)(2.0 * M_PI / 7.0) * (float)k;
        float c1k = cosf(th), s1k = sinf(th);
        float c2k = cosf(2.0f * th), s2k = sinf(2.0f * th);
        float s = a0 + a1v * c1k + a2v * s1k + a3 * c2k + a4 * s2k;
        s = fmaxf(s, 0.0f);
        o0 += s;
        o1 += s * c1k; o2 += s * s1k;
        o3 += s * c2k; o4 += s * s2k;
    }
    const float i7 = 1.0f / 7.0f, t7 = 2.0f / 7.0f;
    float* op = out + (size_t)idx * NQ;
    op[0] = o0 * i7;
    op[1] = o1 * t7; op[2] = o2 * t7;
    op[3] = o3 * t7; op[4] = o4 * t7;
}

// ---------------------------------------------------------------------------
extern "C" void kernel_launch(void* const* d_in, const int* in_sizes, int n_in,
                              void* d_out, int out_size, void* d_ws, size_t ws_size,
                              hipStream_t stream) {
    const float* x    = (const float*)d_in[0];
    const int*   ei   = (const int*)d_in[1];      // int inputs arrive as int32
    const float* pre  = (const float*)d_in[2];
    const float* phi  = (const float*)d_in[3];
    const float* W1   = (const float*)d_in[4];
    const float* b1   = (const float*)d_in[5];
    const float* Ws1  = (const float*)d_in[6];
    const float* W2   = (const float*)d_in[7];
    const float* b2   = (const float*)d_in[8];
    const float* Ws2  = (const float*)d_in[9];
    float* out = (float*)d_out;

    // Workspace layout: Wt1, Wt2, agg1, agg2 (contiguous, zeroed), h
    unsigned short* Wt1 = (unsigned short*)d_ws;          // 128 KB
    unsigned short* Wt2 = Wt1 + WSZ;                      // 128 KB
    float* agg1 = (float*)(Wt2 + WSZ);                    // 3.2 MB
    float* agg2 = agg1 + (size_t)NN * OP;                 // 3.2 MB (contiguous)
    float* h    = agg2 + (size_t)NN * OP;                 // 3.2 MB

    // init: zero agg1+agg2 (400k float4) + build both W tables
    init_ws<<<(400000 + 255) / 256, 256, 0, stream>>>(W1, W2, Wt1, Wt2, (float4*)agg1);

    // Layer 1
    edge_conv_mfma<<<NE / MT, 64, 0, stream>>>(x, ei, pre, phi, Wt1, agg1);
    nonlin_fused<<<(NN * NC + 255) / 256, 256, 0, stream>>>(agg1, x, Ws1, b1, nullptr, h);

    // Layer 2
    edge_conv_mfma<<<NE / MT, 64, 0, stream>>>(h, ei, pre, phi, Wt2, agg2);
    nonlin_fused<<<(NN * NC + 255) / 256, 256, 0, stream>>>(agg2, h, Ws2, b2, x, out);
}